// Round 9
// baseline (242.557 us; speedup 1.0000x reference)
//
#include <hip/hip_runtime.h>

#define N_NODES 100000
#define N_EDGES 1600000
#define D 128
#define RPB 64                        // node rows per bucket
#define NBUCKET 1563                  // ceil(N_NODES / RPB)
#define NBLK 196                      // edge chunks
#define EPB 8192                      // edges per chunk
#define CHO 1564                      // chunkoff row stride (NBUCKET offsets + end)
#define AGG_CAP 2048                  // max edges per bucket (mean 1024, +32 sigma)
#define XCB 3125                      // xconv blocks (3.2M float4 / 1024)
#define SCAN_PAD 1792                 // 256*7 >= NBUCKET

constexpr float LN_EPS   = 1e-5f;
constexpr float MEAN_EPS = 1e-8f;

typedef __attribute__((ext_vector_type(8))) short bf16x8;
typedef __attribute__((ext_vector_type(4))) float f32x4;

__device__ inline float bf2f(unsigned short h) {
  union { unsigned u; float f; } v; v.u = (unsigned)h << 16; return v.f;
}
__device__ inline unsigned short f2bf(float f) {
  union { float f; unsigned u; } v; v.f = f;
  return (unsigned short)((v.u + 0x7FFFu + ((v.u >> 16) & 1u)) >> 16);
}

// ---------------------------------------------------------------------------
// Fused prep: blocks [0,NBLK) = per-chunk bucket sort (hist -> local scan ->
// LDS scatter -> dense coalesced write + chunkoff). [NBLK,NBLK+XCB) = x->bf16.
// Last 16 = W concat + bias. No global scan, no device-wide atomics.
// (unchanged from R8)
// ---------------------------------------------------------------------------
__global__ __launch_bounds__(256) void prep_sort(
    const float* __restrict__ x, const int* __restrict__ ei,
    const float* __restrict__ Wself, const float* __restrict__ Wagg,
    const float* __restrict__ bself, const float* __restrict__ bagg,
    unsigned short* __restrict__ xb, unsigned short* __restrict__ wcat,
    float* __restrict__ bsum, unsigned* __restrict__ ent_sorted,
    int* __restrict__ chunkoff) {
  __shared__ int ent_s[EPB];        // 32 KB
  __shared__ int cnt_s[SCAN_PAD];   // 7 KB
  __shared__ int off_s[SCAN_PAD];   // 7 KB (becomes cursors after chunkoff write)
  __shared__ int sb[256];
  const int bid = blockIdx.x;
  const int t = threadIdx.x;

  if (bid < NBLK) {
    const int ebase = bid * EPB;
    const int nch = min(EPB, N_EDGES - ebase);       // last chunk: 2560
    const int base4 = bid * (EPB / 4);
    const int end4 = base4 + (nch >> 2);             // nch divisible by 4

    for (int i = t; i < SCAN_PAD; i += 256) cnt_s[i] = 0;
    __syncthreads();

    // pass 1: histogram
#pragma unroll
    for (int k = 0; k < EPB / 1024; ++k) {
      int i4 = base4 + k * 256 + t;
      if (i4 < end4) {
        int4 r = ((const int4*)ei)[i4];
        atomicAdd(&cnt_s[r.x >> 6], 1);
        atomicAdd(&cnt_s[r.y >> 6], 1);
        atomicAdd(&cnt_s[r.z >> 6], 1);
        atomicAdd(&cnt_s[r.w >> 6], 1);
      }
    }
    __syncthreads();

    // blocked exclusive scan over SCAN_PAD (=256*7) entries
    int psum = 0;
#pragma unroll
    for (int i = 0; i < 7; ++i) psum += cnt_s[t * 7 + i];
    sb[t] = psum;
    __syncthreads();
    for (int off = 1; off < 256; off <<= 1) {
      int u = (t >= off) ? sb[t - off] : 0;
      __syncthreads();
      sb[t] += u;
      __syncthreads();
    }
    int run = sb[t] - psum;
#pragma unroll
    for (int i = 0; i < 7; ++i) {
      off_s[t * 7 + i] = run;
      run += cnt_s[t * 7 + i];
    }
    __syncthreads();

    // write chunkoff BEFORE scatter destroys off_s
    for (int b = t; b < NBUCKET; b += 256)
      chunkoff[bid * CHO + b] = off_s[b];
    if (t == 0) chunkoff[bid * CHO + NBUCKET] = nch;
    __syncthreads();

    // pass 2: LDS scatter into bucket-sorted order (off_s as cursors)
#pragma unroll
    for (int k = 0; k < EPB / 1024; ++k) {
      int i4 = base4 + k * 256 + t;
      if (i4 < end4) {
        int4 r = ((const int4*)ei)[i4];
        int4 c = ((const int4*)(ei + N_EDGES))[i4];
        int p0 = atomicAdd(&off_s[r.x >> 6], 1);
        ent_s[p0] = ((r.x & 63) << 17) | c.x;
        int p1 = atomicAdd(&off_s[r.y >> 6], 1);
        ent_s[p1] = ((r.y & 63) << 17) | c.y;
        int p2 = atomicAdd(&off_s[r.z >> 6], 1);
        ent_s[p2] = ((r.z & 63) << 17) | c.z;
        int p3 = atomicAdd(&off_s[r.w >> 6], 1);
        ent_s[p3] = ((r.w & 63) << 17) | c.w;
      }
    }
    __syncthreads();

    // dense coalesced write-out
    for (int i = t; i < nch; i += 256)
      ent_sorted[ebase + i] = (unsigned)ent_s[i];
  } else if (bid < NBLK + XCB) {
    // ---- xconv: 4 float4 per thread -> bf16x4
    const int base = (bid - NBLK) * 1024;
#pragma unroll
    for (int k = 0; k < 4; ++k) {
      int i4 = base + k * 256 + t;   // XCB*1024 == 3.2M exact
      float4 v = ((const float4*)x)[i4];
      ushort4 o;
      o.x = f2bf(v.x); o.y = f2bf(v.y); o.z = f2bf(v.z); o.w = f2bf(v.w);
      ((ushort4*)xb)[i4] = o;
    }
  } else {
    // ---- wconv: 16 blocks cover 128x256 weights
    const int blk = bid - NBLK - XCB;
#pragma unroll
    for (int k = 0; k < 8; ++k) {
      int idx = blk * 2048 + k * 256 + t;
      int o = idx >> 8, kc = idx & 255;
      float v = (kc < 128) ? Wself[o * 128 + kc] : Wagg[o * 128 + (kc - 128)];
      wcat[o * 256 + kc] = f2bf(v);
    }
    if (blk == 0 && t < 128) bsum[t] = bself[t] + bagg[t];
  }
}

// ---------------------------------------------------------------------------
// Aggregate: 512 threads (8 waves -> up to 4 blocks/CU = 32 waves/CU).
// Slice gather + row counting sort as R8; gather loop unrolled 4x so each
// wave keeps 4 independent 256B row-loads in flight (latency-bound fix).
// ---------------------------------------------------------------------------
__global__ __launch_bounds__(512) void aggregate(
    const unsigned short* __restrict__ xb, const unsigned* __restrict__ ent_sorted,
    const int* __restrict__ chunkoff, float* out) {
  __shared__ int ent_s[AGG_CAP];   // 8 KB
  __shared__ int col_s[AGG_CAP];   // 8 KB
  __shared__ int sb[256];
  __shared__ int cnt_s[RPB];
  __shared__ int off_s[RPB];
  __shared__ int cur_s[RPB];

  const int b = blockIdx.x;
  const int t = threadIdx.x;

  // slice info + scan of lengths (first 256 threads; NBLK=196 < 256)
  int beg = 0, len = 0;
  if (t < NBLK) {
    beg = chunkoff[t * CHO + b];
    len = chunkoff[t * CHO + b + 1] - beg;
  }
  if (t < 256) sb[t] = len;
  __syncthreads();
  for (int off = 1; off < 256; off <<= 1) {
    int u = (t < 256 && t >= off) ? sb[t - off] : 0;
    __syncthreads();
    if (t < 256) sb[t] += u;
    __syncthreads();
  }
  int n = sb[255]; if (n > AGG_CAP) n = AGG_CAP;
  // parallel slice copy (196 threads, ~5 entries each, contiguous reads)
  if (t < NBLK) {
    int dst = sb[t] - len;
    const unsigned* src = ent_sorted + t * EPB + beg;
    for (int i = 0; i < len; ++i)
      if (dst + i < AGG_CAP) ent_s[dst + i] = (int)src[i];
  }
  __syncthreads();

  // row counting sort
  if (t < RPB) cnt_s[t] = 0;
  __syncthreads();
  for (int i = t; i < n; i += 512) atomicAdd(&cnt_s[ent_s[i] >> 17], 1);
  __syncthreads();
  if (t < RPB) off_s[t] = cnt_s[t];
  __syncthreads();
  for (int off = 1; off < RPB; off <<= 1) {
    int u = 0;
    if (t < RPB && t >= off) u = off_s[t - off];
    __syncthreads();
    if (t < RPB) off_s[t] += u;
    __syncthreads();
  }
  int excl = 0;
  if (t < RPB) excl = off_s[t] - cnt_s[t];
  __syncthreads();
  if (t < RPB) { off_s[t] = excl; cur_s[t] = excl; }
  __syncthreads();
  for (int i = t; i < n; i += 512) {
    int e = ent_s[i];
    int pos = atomicAdd(&cur_s[e >> 17], 1);
    col_s[pos] = e & 0x1FFFF;
  }
  __syncthreads();

  // gather: wave w -> rows w, w+8, ...; 4 lane-groups x 16 lanes x uint4;
  // 4-deep unroll keeps 4 row-loads in flight before any decode.
  const int w = t >> 6, lane = t & 63;
  const int grp = lane >> 4, l = lane & 15;
  const int nodebase = b << 6;
  for (int lrow = w; lrow < RPB; lrow += 8) {
    int node = nodebase + lrow;
    if (node >= N_NODES) break;
    int rbeg = off_s[lrow];
    int deg = cnt_s[lrow];
    float acc[8];
#pragma unroll
    for (int k = 0; k < 8; ++k) acc[k] = 0.f;
    for (int j0 = 0; j0 < deg; j0 += 16) {
      int j1 = j0 + grp, j2 = j0 + 4 + grp, j3 = j0 + 8 + grp, j4 = j0 + 12 + grp;
      bool v1 = j1 < deg, v2 = j2 < deg, v3 = j3 < deg, v4 = j4 < deg;
      uint4 p1, p2, p3, p4;
      if (v1) p1 = *(const uint4*)(xb + (size_t)col_s[rbeg + j1] * D + l * 8);
      if (v2) p2 = *(const uint4*)(xb + (size_t)col_s[rbeg + j2] * D + l * 8);
      if (v3) p3 = *(const uint4*)(xb + (size_t)col_s[rbeg + j3] * D + l * 8);
      if (v4) p4 = *(const uint4*)(xb + (size_t)col_s[rbeg + j4] * D + l * 8);
      if (v1) {
        acc[0] += bf2f((unsigned short)(p1.x & 0xFFFFu));
        acc[1] += bf2f((unsigned short)(p1.x >> 16));
        acc[2] += bf2f((unsigned short)(p1.y & 0xFFFFu));
        acc[3] += bf2f((unsigned short)(p1.y >> 16));
        acc[4] += bf2f((unsigned short)(p1.z & 0xFFFFu));
        acc[5] += bf2f((unsigned short)(p1.z >> 16));
        acc[6] += bf2f((unsigned short)(p1.w & 0xFFFFu));
        acc[7] += bf2f((unsigned short)(p1.w >> 16));
      }
      if (v2) {
        acc[0] += bf2f((unsigned short)(p2.x & 0xFFFFu));
        acc[1] += bf2f((unsigned short)(p2.x >> 16));
        acc[2] += bf2f((unsigned short)(p2.y & 0xFFFFu));
        acc[3] += bf2f((unsigned short)(p2.y >> 16));
        acc[4] += bf2f((unsigned short)(p2.z & 0xFFFFu));
        acc[5] += bf2f((unsigned short)(p2.z >> 16));
        acc[6] += bf2f((unsigned short)(p2.w & 0xFFFFu));
        acc[7] += bf2f((unsigned short)(p2.w >> 16));
      }
      if (v3) {
        acc[0] += bf2f((unsigned short)(p3.x & 0xFFFFu));
        acc[1] += bf2f((unsigned short)(p3.x >> 16));
        acc[2] += bf2f((unsigned short)(p3.y & 0xFFFFu));
        acc[3] += bf2f((unsigned short)(p3.y >> 16));
        acc[4] += bf2f((unsigned short)(p3.z & 0xFFFFu));
        acc[5] += bf2f((unsigned short)(p3.z >> 16));
        acc[6] += bf2f((unsigned short)(p3.w & 0xFFFFu));
        acc[7] += bf2f((unsigned short)(p3.w >> 16));
      }
      if (v4) {
        acc[0] += bf2f((unsigned short)(p4.x & 0xFFFFu));
        acc[1] += bf2f((unsigned short)(p4.x >> 16));
        acc[2] += bf2f((unsigned short)(p4.y & 0xFFFFu));
        acc[3] += bf2f((unsigned short)(p4.y >> 16));
        acc[4] += bf2f((unsigned short)(p4.z & 0xFFFFu));
        acc[5] += bf2f((unsigned short)(p4.z >> 16));
        acc[6] += bf2f((unsigned short)(p4.w & 0xFFFFu));
        acc[7] += bf2f((unsigned short)(p4.w >> 16));
      }
    }
#pragma unroll
    for (int k = 0; k < 8; ++k) {
      acc[k] += __shfl_xor(acc[k], 16, 64);
      acc[k] += __shfl_xor(acc[k], 32, 64);
    }
    if (grp == 0) {
      float inv = 1.0f / ((float)deg + MEAN_EPS);
      uint4 o;
      o.x = (unsigned)f2bf(acc[0] * inv) | ((unsigned)f2bf(acc[1] * inv) << 16);
      o.y = (unsigned)f2bf(acc[2] * inv) | ((unsigned)f2bf(acc[3] * inv) << 16);
      o.z = (unsigned)f2bf(acc[4] * inv) | ((unsigned)f2bf(acc[5] * inv) << 16);
      o.w = (unsigned)f2bf(acc[6] * inv) | ((unsigned)f2bf(acc[7] * inv) << 16);
      ((uint4*)(out + (size_t)node * D))[l] = o;
    }
  }
}

// ---------------------------------------------------------------------------
// MFMA GEMM: C[100000x128] = [x_bf16 | mean_bf16] (K=256) @ Wcat^T  + LN
// (unchanged from R3-R8)
// ---------------------------------------------------------------------------
__global__ __launch_bounds__(512) void gemm_mfma_ln(
    const unsigned short* __restrict__ xb, const float* out_mean,
    const unsigned short* __restrict__ wcat, const float* __restrict__ bsum,
    const float* __restrict__ gamma, const float* __restrict__ beta,
    float* out) {
  __shared__ unsigned short As[128 * 264];
  __shared__ unsigned short Bs[128 * 264];
  __shared__ float bias_s[128];

  const int t = threadIdx.x;
  const int w = t >> 6, lane = t & 63;
  const int q = lane >> 4, s = lane & 15;
  const int base = blockIdx.x * 128;

  if (t < 128) bias_s[t] = bsum[t];

#pragma unroll
  for (int r = 0; r < 8; ++r) {
    int f = r * 512 + t;
    int row = f >> 5, c = f & 31;
    uint4 v = *(const uint4*)(wcat + row * 256 + c * 8);
    *(uint4*)(Bs + row * 264 + c * 8) = v;
  }
#pragma unroll
  for (int r = 0; r < 8; ++r) {
    int f = r * 512 + t;
    int row = f >> 5, c = f & 31;
    int node = base + row;
    uint4 v = make_uint4(0, 0, 0, 0);
    if (node < N_NODES) {
      const unsigned short* src = (c < 16)
          ? xb + (size_t)node * 128 + c * 8
          : (const unsigned short*)(out_mean + (size_t)node * 128) + (c - 16) * 8;
      v = *(const uint4*)src;
    }
    *(uint4*)(As + row * 264 + c * 8) = v;
  }
  __syncthreads();

  const int mrow = (w & 3) * 32;
  const int ncol = (w >> 2) * 64;

  f32x4 acc[2][4];
#pragma unroll
  for (int i = 0; i < 2; ++i)
#pragma unroll
    for (int j = 0; j < 4; ++j) acc[i][j] = (f32x4)(0.0f);

#pragma unroll
  for (int kk = 0; kk < 8; ++kk) {
    int ko = kk * 32 + q * 8;
    bf16x8 a0 = *(const bf16x8*)(As + (mrow + s) * 264 + ko);
    bf16x8 a1 = *(const bf16x8*)(As + (mrow + 16 + s) * 264 + ko);
    bf16x8 bv[4];
#pragma unroll
    for (int j = 0; j < 4; ++j)
      bv[j] = *(const bf16x8*)(Bs + (ncol + j * 16 + s) * 264 + ko);
#pragma unroll
    for (int j = 0; j < 4; ++j) {
      acc[0][j] = __builtin_amdgcn_mfma_f32_16x16x32_bf16(a0, bv[j], acc[0][j], 0, 0, 0);
      acc[1][j] = __builtin_amdgcn_mfma_f32_16x16x32_bf16(a1, bv[j], acc[1][j], 0, 0, 0);
    }
  }
  __syncthreads();

  float* hS = (float*)As;  // [128][132]
#pragma unroll
  for (int i = 0; i < 2; ++i)
#pragma unroll
    for (int j = 0; j < 4; ++j)
#pragma unroll
      for (int r = 0; r < 4; ++r) {
        int row = mrow + i * 16 + q * 4 + r;
        int col = ncol + j * 16 + s;
        float h = acc[i][j][r] + bias_s[col];
        hS[row * 132 + col] = fmaxf(h, 0.0f);
      }
  __syncthreads();

  float gx = gamma[2 * lane], gy = gamma[2 * lane + 1];
  float bx = beta[2 * lane],  by = beta[2 * lane + 1];
#pragma unroll 4
  for (int rr = 0; rr < 16; ++rr) {
    int row = w * 16 + rr;
    int node = base + row;
    float v0 = hS[row * 132 + 2 * lane];
    float v1 = hS[row * 132 + 2 * lane + 1];
    float s1 = v0 + v1, s2 = v0 * v0 + v1 * v1;
#pragma unroll
    for (int m = 1; m < 64; m <<= 1) {
      s1 += __shfl_xor(s1, m, 64);
      s2 += __shfl_xor(s2, m, 64);
    }
    float mu = s1 * (1.0f / 128.0f);
    float var = s2 * (1.0f / 128.0f) - mu * mu;
    float rstd = rsqrtf(var + LN_EPS);
    if (node < N_NODES) {
      float2 o;
      o.x = (v0 - mu) * rstd * gx + bx;
      o.y = (v1 - mu) * rstd * gy + by;
      *(float2*)(out + (size_t)node * 128 + 2 * lane) = o;
    }
  }
}

extern "C" void kernel_launch(void* const* d_in, const int* in_sizes, int n_in,
                              void* d_out, int out_size, void* d_ws, size_t ws_size,
                              hipStream_t stream) {
  const float* x     = (const float*)d_in[0];
  const int*   ei    = (const int*)d_in[1];
  const float* Wagg  = (const float*)d_in[2];
  const float* bagg  = (const float*)d_in[3];
  const float* Wself = (const float*)d_in[4];
  const float* bself = (const float*)d_in[5];
  const float* gamma = (const float*)d_in[6];
  const float* beta  = (const float*)d_in[7];
  float* out = (float*)d_out;

  // ws: xb | wcat | bsum | ent_sorted | chunkoff   (~33.3 MB)
  unsigned short* xb   = (unsigned short*)d_ws;                 // 25.6 MB
  unsigned short* wcat = xb + (size_t)N_NODES * D;              // 64 KB
  float* bsum      = (float*)(wcat + 128 * 256);                // 512 B
  unsigned* ent_sorted = (unsigned*)(bsum + 128);               // NBLK*EPB u32 (6.4 MB)
  int* chunkoff    = (int*)(ent_sorted + (size_t)NBLK * EPB);   // NBLK*CHO (1.23 MB)

  prep_sort<<<NBLK + XCB + 16, 256, 0, stream>>>(
      x, ei, Wself, Wagg, bself, bagg, xb, wcat, bsum, ent_sorted, chunkoff);

  aggregate<<<NBUCKET, 512, 0, stream>>>(xb, ent_sorted, chunkoff, out);

  gemm_mfma_ln<<<(N_NODES + 127) / 128, 512, 0, stream>>>(
      xb, out, wcat, bsum, gamma, beta, out);
}